// Round 12
// baseline (282.401 us; speedup 1.0000x reference)
//
#include <hip/hip_runtime.h>
#include <hip/hip_bf16.h>

typedef unsigned int uint;
typedef unsigned short ushort;
typedef __bf16 bf16;
typedef bf16 bf16x8 __attribute__((ext_vector_type(8)));
typedef float f32x4 __attribute__((ext_vector_type(4)));
typedef ushort ushort4v __attribute__((ext_vector_type(4)));

__device__ __forceinline__ float bf2f(ushort u) {
  union { uint u; float f; } v; v.u = ((uint)u) << 16; return v.f;
}
__device__ __forceinline__ ushort f2bf(float f) {
  union { float f; uint u; } v; v.f = f;
  uint u = v.u;
  uint r = (u + 0x7fffu + ((u >> 16) & 1u)) >> 16;
  return (ushort)r;
}

__device__ __forceinline__ void gl2lds16(const void* g, void* l) {
  __builtin_amdgcn_global_load_lds(
      (const __attribute__((address_space(1))) void*)g,
      (__attribute__((address_space(3))) void*)l, 16, 0, 0);
}

// ---------------------------------------------------------------------------
// LayerNorm single-row worker (mode 0: video f32 -> bf16), wave/row.
// ---------------------------------------------------------------------------
__device__ __forceinline__ void ln_rows0(
    int nrows, int blk, int nblk, int tid,
    const float* __restrict__ srcA,
    const float* __restrict__ g, const float* __restrict__ b,
    ushort* __restrict__ dst)
{
  const int l = tid & 63;
  const int nw = nblk * 4;
  for (int row = blk * 4 + (tid >> 6); row < nrows; row += nw) {
    const float* s = srcA + (size_t)row * 512;
    float x[8];
    float4 a0 = *(const float4*)(s + l * 4);
    float4 a1 = *(const float4*)(s + 256 + l * 4);
    x[0] = a0.x; x[1] = a0.y; x[2] = a0.z; x[3] = a0.w;
    x[4] = a1.x; x[5] = a1.y; x[6] = a1.z; x[7] = a1.w;
    float sum = 0.f, sq = 0.f;
    #pragma unroll
    for (int j = 0; j < 8; ++j) { sum += x[j]; sq += x[j] * x[j]; }
    #pragma unroll
    for (int o = 1; o < 64; o <<= 1) {
      sum += __shfl_xor(sum, o);
      sq  += __shfl_xor(sq, o);
    }
    float mu = sum * (1.f / 512.f);
    float var = sq * (1.f / 512.f) - mu * mu;
    float rstd = rsqrtf(var + 1e-5f);
    float4 g0 = *(const float4*)(g + l * 4);
    float4 g1 = *(const float4*)(g + 256 + l * 4);
    float4 b0 = *(const float4*)(b + l * 4);
    float4 b1 = *(const float4*)(b + 256 + l * 4);
    float gv[8] = {g0.x,g0.y,g0.z,g0.w,g1.x,g1.y,g1.z,g1.w};
    float bv[8] = {b0.x,b0.y,b0.z,b0.w,b1.x,b1.y,b1.z,b1.w};
    ushort* d = dst + (size_t)row * 512;
    ushort4v p0, p1;
    #pragma unroll
    for (int j = 0; j < 4; ++j) {
      p0[j] = f2bf((x[j] - mu) * rstd * gv[j] + bv[j]);
      p1[j] = f2bf((x[4+j] - mu) * rstd * gv[4+j] + bv[4+j]);
    }
    *(ushort4v*)(d + l * 4) = p0;
    *(ushort4v*)(d + 256 + l * 4) = p1;
  }
}

// ---------------------------------------------------------------------------
// Pair-row LayerNorm, mode 1 only (music f32 gather -> bf16), 2 rows/wave.
// ---------------------------------------------------------------------------
__device__ __forceinline__ void ln_pair1(
    int wid, int tid,
    const float* __restrict__ srcA,
    const float* __restrict__ g, const float* __restrict__ b,
    ushort* __restrict__ dst)
{
  const int l = tid & 63;
  const int r0 = wid * 2, r1 = r0 + 1;
  float x0[8], x1[8];
  int mm0 = r0 >> 9, fi0 = r0 & 511;
  int mm1 = r1 >> 9, fi1 = r1 & 511;
  const float* s0 = srcA + ((size_t)mm0 * 514 + 2 + fi0) * 512;
  const float* s1 = srcA + ((size_t)mm1 * 514 + 2 + fi1) * 512;
  float4 a0 = *(const float4*)(s0 + l * 4);
  float4 a1 = *(const float4*)(s0 + 256 + l * 4);
  float4 c0 = *(const float4*)(s1 + l * 4);
  float4 c1 = *(const float4*)(s1 + 256 + l * 4);
  x0[0]=a0.x; x0[1]=a0.y; x0[2]=a0.z; x0[3]=a0.w;
  x0[4]=a1.x; x0[5]=a1.y; x0[6]=a1.z; x0[7]=a1.w;
  x1[0]=c0.x; x1[1]=c0.y; x1[2]=c0.z; x1[3]=c0.w;
  x1[4]=c1.x; x1[5]=c1.y; x1[6]=c1.z; x1[7]=c1.w;
  float s0v = 0.f, q0 = 0.f, s1v = 0.f, q1 = 0.f;
  #pragma unroll
  for (int j = 0; j < 8; ++j) {
    s0v += x0[j]; q0 += x0[j] * x0[j];
    s1v += x1[j]; q1 += x1[j] * x1[j];
  }
  #pragma unroll
  for (int o = 1; o < 64; o <<= 1) {
    s0v += __shfl_xor(s0v, o); q0 += __shfl_xor(q0, o);
    s1v += __shfl_xor(s1v, o); q1 += __shfl_xor(q1, o);
  }
  float mu0 = s0v * (1.f/512.f), mu1 = s1v * (1.f/512.f);
  float rstd0 = rsqrtf(q0 * (1.f/512.f) - mu0 * mu0 + 1e-5f);
  float rstd1 = rsqrtf(q1 * (1.f/512.f) - mu1 * mu1 + 1e-5f);
  float4 g0 = *(const float4*)(g + l * 4);
  float4 g1v = *(const float4*)(g + 256 + l * 4);
  float4 b0 = *(const float4*)(b + l * 4);
  float4 b1v = *(const float4*)(b + 256 + l * 4);
  float gv[8] = {g0.x,g0.y,g0.z,g0.w,g1v.x,g1v.y,g1v.z,g1v.w};
  float bv[8] = {b0.x,b0.y,b0.z,b0.w,b1v.x,b1v.y,b1v.z,b1v.w};
  ushort* d0 = dst + (size_t)r0 * 512;
  ushort* d1 = dst + (size_t)r1 * 512;
  ushort4v p00, p01, p10, p11;
  #pragma unroll
  for (int j = 0; j < 4; ++j) {
    p00[j] = f2bf((x0[j]-mu0)*rstd0*gv[j]+bv[j]);
    p01[j] = f2bf((x0[4+j]-mu0)*rstd0*gv[4+j]+bv[4+j]);
    p10[j] = f2bf((x1[j]-mu1)*rstd1*gv[j]+bv[j]);
    p11[j] = f2bf((x1[4+j]-mu1)*rstd1*gv[4+j]+bv[4+j]);
  }
  *(ushort4v*)(d0 + l * 4) = p00;
  *(ushort4v*)(d0 + 256 + l * 4) = p01;
  *(ushort4v*)(d1 + l * 4) = p10;
  *(ushort4v*)(d1 + 256 + l * 4) = p11;
}

// ---------------------------------------------------------------------------
// Preamble: blocks 0-639 cast 5 weights, 640-671 ln0 (video), 672+ ln1 music.
// ---------------------------------------------------------------------------
struct PreArgs {
  const float* s0; const float* s1; const float* s2; const float* s3; const float* s4;
  ushort* d0; ushort* d1; ushort* d2; ushort* d3; ushort* d4;
  const float* video; const float* music;
  const float* g1; const float* b1;
  ushort* veln; ushort* mfln;
};
__global__ __launch_bounds__(256) void preamble(PreArgs a) {
  int bb = blockIdx.x;
  if (bb < 640) {
    int t = bb * 256 + threadIdx.x;
    int which = t >> 15;
    int e = (t & 32767) * 8;
    const float* s = which == 0 ? a.s0 : which == 1 ? a.s1 : which == 2 ? a.s2 : which == 3 ? a.s3 : a.s4;
    ushort*      d = which == 0 ? a.d0 : which == 1 ? a.d1 : which == 2 ? a.d2 : which == 3 ? a.d3 : a.d4;
    float4 v0 = *(const float4*)(s + e);
    float4 v1 = *(const float4*)(s + e + 4);
    uint4 o;
    o.x = (uint)f2bf(v0.x) | ((uint)f2bf(v0.y) << 16);
    o.y = (uint)f2bf(v0.z) | ((uint)f2bf(v0.w) << 16);
    o.z = (uint)f2bf(v1.x) | ((uint)f2bf(v1.y) << 16);
    o.w = (uint)f2bf(v1.z) | ((uint)f2bf(v1.w) << 16);
    *(uint4*)(d + e) = o;
  } else if (bb < 672) {
    ln_rows0(128, bb - 640, 32, threadIdx.x, a.video, a.g1, a.b1, a.veln);
  } else {
    ln_pair1((bb - 672) * 4 + (threadIdx.x >> 6), threadIdx.x,
             a.music, a.g1, a.b1, a.mfln);
  }
}

// ---------------------------------------------------------------------------
// Fused K+V(+Q) projection. BM=256, BN=128 per output, BK=32, 512 threads =
// 8 waves (4 row x 2 col). LDS 64 KB dbuf -> 2 blocks/CU (inter-block
// overlap). Dispatch remap: flat = y*4+x; decode x=flat>>8, y=flat&255 so the
// 4 col-blocks of one row-tile sit at flat = y (mod 8) -> same XCD L2 ->
// A-panel fetched from HBM once.
// 32-col LDS swizzle: chunk c = j ^ ((row>>1)&3) (8 banks x 2-way, free).
// grid (4, 257) flat 0..1027: flats 1024..1027 are the q col-blocks.
// ---------------------------------------------------------------------------
__global__ __launch_bounds__(512) void gemm_kvq(
    const ushort* __restrict__ Amf, const ushort* __restrict__ Aq,
    const ushort* __restrict__ Wk, const ushort* __restrict__ Wv,
    const ushort* __restrict__ Wq,
    const float* __restrict__ bk, const float* __restrict__ bv,
    const float* __restrict__ bq,
    ushort* __restrict__ K, ushort* __restrict__ Vt, ushort* __restrict__ Q)
{
  __shared__ __align__(16) ushort As[2][256 * 32];    // 32 KB
  __shared__ __align__(16) ushort Bks[2][128 * 32];   // 16 KB
  __shared__ __align__(16) ushort Bvs[2][128 * 32];   // 16 KB
  const int tid = threadIdx.x;
  const int w = tid >> 6, l = tid & 63;
  const int lg = l >> 4, lr = l & 15;
  const int wr = w >> 1, wc = w & 1;

  const int flat = blockIdx.y * 4 + blockIdx.x;
  const bool isq = (flat >= 1024);
  const int xb = isq ? (flat - 1024) : (flat >> 8);
  const int yb = isq ? 0 : (flat & 255);
  const int row0 = yb * 256;
  const int col0 = xb * 128;
  const ushort* Ap  = isq ? Aq : Amf;
  const ushort* Wkp = isq ? Wq : Wk;

  f32x4 kacc[4][4], vacc[4][4];
  #pragma unroll
  for (int i = 0; i < 4; i++)
    #pragma unroll
    for (int j = 0; j < 4; j++) {
      f32x4 z = {0.f,0.f,0.f,0.f};
      kacc[i][j] = z; vacc[i][j] = z;
    }

  // staging maps (BK=32): A = 2 issues x (128 rows x 4 chunks), B = 1 issue
  size_t asrc[2], wsrc; int aldst[2], wldst;
  {
    int j = tid & 3;
    #pragma unroll
    for (int i = 0; i < 2; ++i) {
      int r = i * 128 + (tid >> 2);
      int koff = (j ^ ((r >> 1) & 3)) * 8;
      asrc[i] = (size_t)(row0 + r) * 512 + koff;
      aldst[i] = i * 4096 + w * 512;   // elems; wave-uniform base
    }
    int r = tid >> 2;
    int koff = (j ^ ((r >> 1) & 3)) * 8;
    wsrc = (size_t)(col0 + r) * 512 + koff;
    wldst = w * 512;
  }

  auto stage = [&](int pb, int kk) {
    #pragma unroll
    for (int i = 0; i < 2; ++i)
      gl2lds16(Ap + asrc[i] + kk * 32, &As[pb][aldst[i]]);
    gl2lds16(Wkp + wsrc + kk * 32, &Bks[pb][wldst]);
    gl2lds16(Wv + wsrc + kk * 32, &Bvs[pb][wldst]);
  };
  auto compute = [&](int pb) {
    bf16x8 af[4], bkf[4];
    #pragma unroll
    for (int mi = 0; mi < 4; ++mi) {
      int r = wr * 64 + mi * 16 + lr;
      int c = lg ^ ((r >> 1) & 3);
      af[mi] = *(const bf16x8*)(&As[pb][r * 32 + c * 8]);
    }
    #pragma unroll
    for (int ni = 0; ni < 4; ++ni) {
      int r = wc * 64 + ni * 16 + lr;
      int c = lg ^ ((r >> 1) & 3);
      bkf[ni] = *(const bf16x8*)(&Bks[pb][r * 32 + c * 8]);
    }
    __builtin_amdgcn_s_setprio(1);
    #pragma unroll
    for (int mi = 0; mi < 4; ++mi)
      #pragma unroll
      for (int ni = 0; ni < 4; ++ni)
        kacc[mi][ni] = __builtin_amdgcn_mfma_f32_16x16x32_bf16(af[mi], bkf[ni], kacc[mi][ni], 0, 0, 0);
    __builtin_amdgcn_s_setprio(0);
    if (!isq) {
      bf16x8 bvf[4];
      #pragma unroll
      for (int ni = 0; ni < 4; ++ni) {
        int r = wc * 64 + ni * 16 + lr;
        int c = lg ^ ((r >> 1) & 3);
        bvf[ni] = *(const bf16x8*)(&Bvs[pb][r * 32 + c * 8]);
      }
      __builtin_amdgcn_s_setprio(1);
      #pragma unroll
      for (int mi = 0; mi < 4; ++mi)
        #pragma unroll
        for (int ni = 0; ni < 4; ++ni)
          vacc[mi][ni] = __builtin_amdgcn_mfma_f32_16x16x32_bf16(af[mi], bvf[ni], vacc[mi][ni], 0, 0, 0);
      __builtin_amdgcn_s_setprio(0);
    }
  };

  stage(0, 0);
  __syncthreads();
  int cur = 0;
  #pragma unroll
  for (int kk = 0; kk < 15; ++kk) {
    stage(cur ^ 1, kk + 1);
    compute(cur);
    __syncthreads();
    cur ^= 1;
  }
  compute(cur);

  #pragma unroll
  for (int ni = 0; ni < 4; ++ni) {
    int cg = col0 + wc * 64 + ni * 16 + lr;
    float bkc = isq ? bq[cg] : bk[cg];
    float bvc = isq ? 0.f : bv[cg];
    #pragma unroll
    for (int mi = 0; mi < 4; ++mi) {
      int rg0 = row0 + wr * 64 + mi * 16 + lg * 4;
      if (isq) {
        if (rg0 < 128) {
          #pragma unroll
          for (int e = 0; e < 4; ++e)
            Q[(size_t)(rg0 + e) * 512 + cg] = f2bf((kacc[mi][ni][e] + bkc) * 0.125f);
        }
      } else {
        #pragma unroll
        for (int e = 0; e < 4; ++e)
          K[(size_t)(rg0 + e) * 512 + cg] = f2bf(kacc[mi][ni][e] + bkc);
        int m = rg0 >> 9, fi = rg0 & 511;
        ushort4v pk;
        #pragma unroll
        for (int e = 0; e < 4; ++e) pk[e] = f2bf(vacc[mi][ni][e] + bvc);
        *(ushort4v*)(Vt + (size_t)(m * 512 + cg) * 512 + fi) = pk;
      }
    }
  }
}

// ---------------------------------------------------------------------------
// Fused GEMM + row-LayerNorm (R11-proven). BM=64, BN=512, BK=64, 8 waves.
// ---------------------------------------------------------------------------
__global__ __launch_bounds__(512) void gemm_ln(
    const ushort* __restrict__ A, const ushort* __restrict__ W,
    const float* __restrict__ bias,
    const float* __restrict__ gam, const float* __restrict__ bet,
    void* __restrict__ outp, const ushort* __restrict__ resid, int outf32)
{
  __shared__ __align__(16) ushort As[2][64 * 64];
  __shared__ __align__(16) ushort Bs[2][512 * 64];
  __shared__ float red[8][64][2];
  const int tid = threadIdx.x;
  const int w = tid >> 6, l = tid & 63;
  const int lg = l >> 4, lr = l & 15;
  const int row0 = blockIdx.x * 64;

  f32x4 acc[4][4];
  #pragma unroll
  for (int i = 0; i < 4; i++)
    #pragma unroll
    for (int j = 0; j < 4; j++) { f32x4 z = {0.f,0.f,0.f,0.f}; acc[i][j] = z; }

  size_t asrc, wsrc0; int aldst;
  {
    int r = tid >> 3, j = tid & 7;
    int koff = (j ^ (r & 7)) * 8;
    asrc = (size_t)(row0 + r) * 512 + koff;
    wsrc0 = (size_t)r * 512 + koff;
    aldst = (w * 8) * 64;
  }

  auto stage = [&](int pb, int kk) {
    gl2lds16(A + asrc + kk * 64, &As[pb][aldst]);
    #pragma unroll
    for (int b = 0; b < 8; ++b)
      gl2lds16(W + wsrc0 + (size_t)b * 32768 + kk * 64,
               &Bs[pb][(b * 64 + w * 8) * 64]);
  };
  auto compute = [&](int pb) {
    #pragma unroll
    for (int ks = 0; ks < 2; ++ks) {
      bf16x8 af[4], bfr[4];
      #pragma unroll
      for (int mi = 0; mi < 4; ++mi) {
        int ra = mi * 16 + lr;
        af[mi] = *(const bf16x8*)(&As[pb][ra * 64 + ((ks * 32 + lg * 8) ^ ((ra & 7) * 8))]);
      }
      #pragma unroll
      for (int ni = 0; ni < 4; ++ni) {
        int rb = w * 64 + ni * 16 + lr;
        bfr[ni] = *(const bf16x8*)(&Bs[pb][rb * 64 + ((ks * 32 + lg * 8) ^ ((rb & 7) * 8))]);
      }
      __builtin_amdgcn_s_setprio(1);
      #pragma unroll
      for (int mi = 0; mi < 4; ++mi)
        #pragma unroll
        for (int ni = 0; ni < 4; ++ni)
          acc[mi][ni] = __builtin_amdgcn_mfma_f32_16x16x32_bf16(af[mi], bfr[ni], acc[mi][ni], 0, 0, 0);
      __builtin_amdgcn_s_setprio(0);
    }
  };

  stage(0, 0);
  __syncthreads();
  int cur = 0;
  #pragma unroll
  for (int kk = 0; kk < 7; ++kk) {
    stage(cur ^ 1, kk + 1);
    compute(cur);
    __syncthreads();
    cur ^= 1;
  }
  compute(cur);

  float bc[4], gv[4], bv2[4];
  #pragma unroll
  for (int ni = 0; ni < 4; ++ni) {
    int col = w * 64 + ni * 16 + lr;
    bc[ni] = bias[col];
    gv[ni] = gam[col];
    bv2[ni] = bet[col];
  }
  #pragma unroll
  for (int mi = 0; mi < 4; ++mi)
    #pragma unroll
    for (int e = 0; e < 4; ++e) {
      int row = row0 + mi * 16 + lg * 4 + e;
      #pragma unroll
      for (int ni = 0; ni < 4; ++ni) {
        float v = acc[mi][ni][e] + bc[ni];
        if (resid) v += bf2f(resid[(size_t)row * 512 + w * 64 + ni * 16 + lr]);
        acc[mi][ni][e] = v;
      }
    }
  #pragma unroll
  for (int mi = 0; mi < 4; ++mi)
    #pragma unroll
    for (int e = 0; e < 4; ++e) {
      float s = acc[mi][0][e] + acc[mi][1][e] + acc[mi][2][e] + acc[mi][3][e];
      float q = acc[mi][0][e]*acc[mi][0][e] + acc[mi][1][e]*acc[mi][1][e]
              + acc[mi][2][e]*acc[mi][2][e] + acc[mi][3][e]*acc[mi][3][e];
      #pragma unroll
      for (int o = 1; o < 16; o <<= 1) { s += __shfl_xor(s, o); q += __shfl_xor(q, o); }
      if (lr == 0) {
        int row = mi * 16 + lg * 4 + e;
        red[w][row][0] = s;
        red[w][row][1] = q;
      }
    }
  __syncthreads();
  #pragma unroll
  for (int mi = 0; mi < 4; ++mi)
    #pragma unroll
    for (int e = 0; e < 4; ++e) {
      int row = mi * 16 + lg * 4 + e;
      float S = 0.f, Qm = 0.f;
      #pragma unroll
      for (int w2 = 0; w2 < 8; ++w2) { S += red[w2][row][0]; Qm += red[w2][row][1]; }
      float mu = S * (1.f / 512.f);
      float var = Qm * (1.f / 512.f) - mu * mu;
      float rstd = rsqrtf(var + 1e-5f);
      int grow = row0 + row;
      if (!outf32) {
        ushort* o = (ushort*)outp;
        #pragma unroll
        for (int ni = 0; ni < 4; ++ni)
          o[(size_t)grow * 512 + w * 64 + ni * 16 + lr] =
              f2bf((acc[mi][ni][e] - mu) * rstd * gv[ni] + bv2[ni]);
      } else {
        float* o = (float*)outp;
        #pragma unroll
        for (int ni = 0; ni < 4; ++ni)
          o[(size_t)grow * 512 + w * 64 + ni * 16 + lr] =
              (acc[mi][ni][e] - mu) * rstd * gv[ni] + bv2[ni];
      }
    }
}

// ---------------------------------------------------------------------------
// Attention: one block per (m,h). 4 waves x 32 v-rows. Flash-style over f.
// K/V staging double-buffered; defer-max (T13). (R9-proven)
// ---------------------------------------------------------------------------
__global__ __launch_bounds__(256) void attn_kernel(
    const ushort* __restrict__ q, const ushort* __restrict__ k,
    const ushort* __restrict__ vt, const int* __restrict__ masks,
    ushort* __restrict__ attn)
{
  __shared__ __align__(16) ushort Qs[128 * 64];
  __shared__ __align__(16) ushort Ks[2][64 * 64];
  __shared__ __align__(16) ushort Vs[2][64 * 64];
  __shared__ __align__(16) ushort Ps[4][32 * 64];
  __shared__ float maskf[2][64];
  __shared__ float stats[4][32];

  const int tid = threadIdx.x;
  const int w = tid >> 6, l = tid & 63;
  const int lg = l >> 4, lr = l & 15;
  const int m = blockIdx.x >> 3, h = blockIdx.x & 7;

  const size_t kbase = (size_t)(m * 512) * 512 + h * 64;
  const size_t vbase = (size_t)(m * 512 + h * 64) * 512;

  auto stageKV = [&](int pb, int it) {
    const int f0 = it * 64;
    #pragma unroll
    for (int c2 = 0; c2 < 2; ++c2) {
      int c = c2 * 256 + tid;
      int r = c >> 3, j = c & 7;
      int off = (j * 8) ^ ((r & 7) * 8);
      gl2lds16(k + kbase + (size_t)(f0 + r) * 512 + off, &Ks[pb][(c2 * 256 + w * 64) * 8]);
      gl2lds16(vt + vbase + (size_t)r * 512 + f0 + off, &Vs[pb][(c2 * 256 + w * 64) * 8]);
    }
    if (tid < 64) maskf[pb][tid] = masks[m * 512 + f0 + tid] ? 0.f : -1e30f;
  };

  #pragma unroll
  for (int c2 = 0; c2 < 4; ++c2) {
    int c = c2 * 256 + tid;
    int r = c >> 3, j = c & 7;
    gl2lds16(q + (size_t)r * 512 + h * 64 + ((j * 8) ^ ((r & 7) * 8)),
             Qs + (c2 * 256 + w * 64) * 8);
  }
  stageKV(0, 0);
  __syncthreads();

  f32x4 acc[2][4];
  #pragma unroll
  for (int i = 0; i < 2; i++)
    #pragma unroll
    for (int j = 0; j < 4; j++) { f32x4 z = {0.f,0.f,0.f,0.f}; acc[i][j] = z; }
  float m_run[2] = {-INFINITY, -INFINITY};
  float l_run[2] = {0.f, 0.f};
  bf16x8 qf[2][2];
  #pragma unroll
  for (int nv = 0; nv < 2; ++nv)
    #pragma unroll
    for (int k2 = 0; k2 < 2; ++k2) {
      int v = w * 32 + nv * 16 + lr;
      qf[nv][k2] = *(const bf16x8*)(Qs + v * 64 + ((k2 * 32 + lg * 8) ^ ((v & 7) * 8)));
    }

  int cur = 0;
  for (int it = 0; it < 8; ++it) {
    if (it < 7) stageKV(cur ^ 1, it + 1);

    f32x4 s[4][2];
    #pragma unroll
    for (int mi = 0; mi < 4; mi++)
      #pragma unroll
      for (int nv = 0; nv < 2; nv++) { f32x4 z = {0.f,0.f,0.f,0.f}; s[mi][nv] = z; }
    #pragma unroll
    for (int k2 = 0; k2 < 2; ++k2) {
      bf16x8 kf[4];
      #pragma unroll
      for (int mi = 0; mi < 4; ++mi) {
        int f = mi * 16 + lr;
        kf[mi] = *(const bf16x8*)(&Ks[cur][f * 64 + ((k2 * 32 + lg * 8) ^ ((f & 7) * 8))]);
      }
      __builtin_amdgcn_s_setprio(1);
      #pragma unroll
      for (int mi = 0; mi < 4; ++mi)
        #pragma unroll
        for (int nv = 0; nv < 2; ++nv)
          s[mi][nv] = __builtin_amdgcn_mfma_f32_16x16x32_bf16(kf[mi], qf[nv][k2], s[mi][nv], 0, 0, 0);
      __builtin_amdgcn_s_setprio(0);
    }

    float mk[4][4];
    #pragma unroll
    for (int mi = 0; mi < 4; mi++)
      #pragma unroll
      for (int e = 0; e < 4; e++) mk[mi][e] = maskf[cur][mi * 16 + lg * 4 + e];

    #pragma unroll
    for (int nv = 0; nv < 2; ++nv) {
      float pmax = -INFINITY;
      #pragma unroll
      for (int mi = 0; mi < 4; mi++)
        #pragma unroll
        for (int e = 0; e < 4; e++) {
          s[mi][nv][e] += mk[mi][e];
          pmax = fmaxf(pmax, s[mi][nv][e]);
        }
      pmax = fmaxf(pmax, __shfl_xor(pmax, 16));
      pmax = fmaxf(pmax, __shfl_xor(pmax, 32));
      bool skip = __all(pmax - m_run[nv] <= 8.f);
      float mnew = skip ? m_run[nv] : fmaxf(m_run[nv], pmax);
      float sc = skip ? 1.f : __expf(m_run[nv] - mnew);
      float csum = 0.f;
      int vloc = nv * 16 + lr;
      #pragma unroll
      for (int mi = 0; mi < 4; mi++) {
        ushort4v pk;
        #pragma unroll
        for (int e = 0; e < 4; e++) {
          float p = __expf(s[mi][nv][e] - mnew);
          csum += p;
          pk[e] = f2bf(p);
        }
        int f = mi * 16 + lg * 4;
        *(ushort4v*)(&Ps[w][vloc * 64 + (f ^ ((vloc & 7) * 8))]) = pk;
      }
      csum += __shfl_xor(csum, 16);
      csum += __shfl_xor(csum, 32);
      l_run[nv] = l_run[nv] * sc + csum;
      m_run[nv] = mnew;
      if (lg == 0) stats[w][vloc] = sc;
      if (!skip) {
        int mi2 = nv;
        #pragma unroll
        for (int e = 0; e < 4; ++e) {
          float scv = stats[w][mi2 * 16 + lg * 4 + e];
          #pragma unroll
          for (int nd = 0; nd < 4; ++nd) acc[mi2][nd][e] *= scv;
        }
      }
    }

    #pragma unroll
    for (int k2 = 0; k2 < 2; ++k2) {
      bf16x8 pf[2], vf[4];
      #pragma unroll
      for (int mi2 = 0; mi2 < 2; ++mi2) {
        int vloc = mi2 * 16 + lr;
        pf[mi2] = *(const bf16x8*)(&Ps[w][vloc * 64 + ((k2 * 32 + lg * 8) ^ ((vloc & 7) * 8))]);
      }
      #pragma unroll
      for (int nd = 0; nd < 4; ++nd) {
        int d = nd * 16 + lr;
        vf[nd] = *(const bf16x8*)(&Vs[cur][d * 64 + ((k2 * 32 + lg * 8) ^ ((d & 7) * 8))]);
      }
      __builtin_amdgcn_s_setprio(1);
      #pragma unroll
      for (int mi2 = 0; mi2 < 2; ++mi2)
        #pragma unroll
        for (int nd = 0; nd < 4; ++nd)
          acc[mi2][nd] = __builtin_amdgcn_mfma_f32_16x16x32_bf16(pf[mi2], vf[nd], acc[mi2][nd], 0, 0, 0);
      __builtin_amdgcn_s_setprio(0);
    }
    __syncthreads();
    cur ^= 1;
  }

  #pragma unroll
  for (int nv = 0; nv < 2; ++nv)
    if (lg == 0) stats[w][nv * 16 + lr] = 1.f / l_run[nv];
  #pragma unroll
  for (int mi2 = 0; mi2 < 2; ++mi2)
    #pragma unroll
    for (int e = 0; e < 4; ++e) {
      float invl = stats[w][mi2 * 16 + lg * 4 + e];
      int vg = w * 32 + mi2 * 16 + lg * 4 + e;
      #pragma unroll
      for (int nd = 0; nd < 4; ++nd) {
        int d = nd * 16 + lr;
        attn[(size_t)(vg * 128 + m) * 512 + h * 64 + d] = f2bf(acc[mi2][nd][e] * invl);
      }
    }
}

// ---------------------------------------------------------------------------
extern "C" void kernel_launch(void* const* d_in, const int* in_sizes, int n_in,
                              void* d_out, int out_size, void* d_ws, size_t ws_size,
                              hipStream_t stream) {
  const float* video = (const float*)d_in[0];
  const float* music = (const float*)d_in[1];
  const int*   masks = (const int*)d_in[2];
  const float* Wq = (const float*)d_in[3];
  const float* Wk = (const float*)d_in[4];
  const float* Wv = (const float*)d_in[5];
  const float* Wo = (const float*)d_in[6];
  const float* Wl = (const float*)d_in[7];
  const float* bq = (const float*)d_in[8];
  const float* bk = (const float*)d_in[9];
  const float* bv = (const float*)d_in[10];
  const float* bo = (const float*)d_in[11];
  const float* bl = (const float*)d_in[12];
  const float* g1 = (const float*)d_in[13];
  const float* g2 = (const float*)d_in[14];
  const float* g3 = (const float*)d_in[15];
  const float* b1 = (const float*)d_in[16];
  const float* b2 = (const float*)d_in[17];
  const float* b3 = (const float*)d_in[18];

  char* ws = (char*)d_ws;
  ushort* mfln = (ushort*)(ws);                    // 65536x512 bf16
  ushort* kbuf = (ushort*)(ws + 67108864);         // 65536x512 bf16
  ushort* vtb  = (ushort*)(ws + 134217728);        // 65536x512 bf16 (transposed per m)
  ushort* attn = (ushort*)(ws + 201326592);        // 16384x512 bf16
  ushort* xbuf = (ushort*)(ws + 234881024);        // 16384x512 bf16
  ushort* veln = (ushort*)(ws + 251658240);        // 128x512 bf16
  ushort* qbuf = (ushort*)(ws + 251789312);        // 128x512 bf16
  ushort* wqb  = (ushort*)(ws + 251920384);
  ushort* wkb  = wqb + 262144;
  ushort* wvb  = wkb + 262144;
  ushort* wob  = wvb + 262144;
  ushort* wlb  = wob + 262144;

  PreArgs pa = {Wq, Wk, Wv, Wo, Wl, wqb, wkb, wvb, wob, wlb,
                video, music, g1, b1, veln, mfln};
  preamble<<<8864, 256, 0, stream>>>(pa);

  gemm_kvq<<<dim3(4, 257), 512, 0, stream>>>(
      mfln, veln, wkb, wvb, wqb, bk, bv, bq, kbuf, vtb, qbuf);

  attn_kernel<<<1024, 256, 0, stream>>>(qbuf, kbuf, vtb, masks, attn);

  gemm_ln<<<256, 512, 0, stream>>>(attn, wob, bo, g2, b2, xbuf, nullptr, 0);
  gemm_ln<<<256, 512, 0, stream>>>(xbuf, wlb, bl, g3, b3, d_out, xbuf, 1);
}

// Round 13
// 265.092 us; speedup vs baseline: 1.0653x; 1.0653x over previous
//
#include <hip/hip_runtime.h>
#include <hip/hip_bf16.h>

typedef unsigned int uint;
typedef unsigned short ushort;
typedef __bf16 bf16;
typedef bf16 bf16x8 __attribute__((ext_vector_type(8)));
typedef float f32x4 __attribute__((ext_vector_type(4)));
typedef ushort ushort4v __attribute__((ext_vector_type(4)));

__device__ __forceinline__ float bf2f(ushort u) {
  union { uint u; float f; } v; v.u = ((uint)u) << 16; return v.f;
}
__device__ __forceinline__ ushort f2bf(float f) {
  union { float f; uint u; } v; v.f = f;
  uint u = v.u;
  uint r = (u + 0x7fffu + ((u >> 16) & 1u)) >> 16;
  return (ushort)r;
}

__device__ __forceinline__ void gl2lds16(const void* g, void* l) {
  __builtin_amdgcn_global_load_lds(
      (const __attribute__((address_space(1))) void*)g,
      (__attribute__((address_space(3))) void*)l, 16, 0, 0);
}

// ---------------------------------------------------------------------------
// LayerNorm single-row worker (mode 0: video f32 -> bf16), wave/row.
// ---------------------------------------------------------------------------
__device__ __forceinline__ void ln_rows0(
    int nrows, int blk, int nblk, int tid,
    const float* __restrict__ srcA,
    const float* __restrict__ g, const float* __restrict__ b,
    ushort* __restrict__ dst)
{
  const int l = tid & 63;
  const int nw = nblk * 4;
  for (int row = blk * 4 + (tid >> 6); row < nrows; row += nw) {
    const float* s = srcA + (size_t)row * 512;
    float x[8];
    float4 a0 = *(const float4*)(s + l * 4);
    float4 a1 = *(const float4*)(s + 256 + l * 4);
    x[0] = a0.x; x[1] = a0.y; x[2] = a0.z; x[3] = a0.w;
    x[4] = a1.x; x[5] = a1.y; x[6] = a1.z; x[7] = a1.w;
    float sum = 0.f, sq = 0.f;
    #pragma unroll
    for (int j = 0; j < 8; ++j) { sum += x[j]; sq += x[j] * x[j]; }
    #pragma unroll
    for (int o = 1; o < 64; o <<= 1) {
      sum += __shfl_xor(sum, o);
      sq  += __shfl_xor(sq, o);
    }
    float mu = sum * (1.f / 512.f);
    float var = sq * (1.f / 512.f) - mu * mu;
    float rstd = rsqrtf(var + 1e-5f);
    float4 g0 = *(const float4*)(g + l * 4);
    float4 g1 = *(const float4*)(g + 256 + l * 4);
    float4 b0 = *(const float4*)(b + l * 4);
    float4 b1 = *(const float4*)(b + 256 + l * 4);
    float gv[8] = {g0.x,g0.y,g0.z,g0.w,g1.x,g1.y,g1.z,g1.w};
    float bv[8] = {b0.x,b0.y,b0.z,b0.w,b1.x,b1.y,b1.z,b1.w};
    ushort* d = dst + (size_t)row * 512;
    ushort4v p0, p1;
    #pragma unroll
    for (int j = 0; j < 4; ++j) {
      p0[j] = f2bf((x[j] - mu) * rstd * gv[j] + bv[j]);
      p1[j] = f2bf((x[4+j] - mu) * rstd * gv[4+j] + bv[4+j]);
    }
    *(ushort4v*)(d + l * 4) = p0;
    *(ushort4v*)(d + 256 + l * 4) = p1;
  }
}

// ---------------------------------------------------------------------------
// Pair-row LayerNorm, mode 1 only (music f32 gather -> bf16), 2 rows/wave.
// ---------------------------------------------------------------------------
__device__ __forceinline__ void ln_pair1(
    int wid, int tid,
    const float* __restrict__ srcA,
    const float* __restrict__ g, const float* __restrict__ b,
    ushort* __restrict__ dst)
{
  const int l = tid & 63;
  const int r0 = wid * 2, r1 = r0 + 1;
  float x0[8], x1[8];
  int mm0 = r0 >> 9, fi0 = r0 & 511;
  int mm1 = r1 >> 9, fi1 = r1 & 511;
  const float* s0 = srcA + ((size_t)mm0 * 514 + 2 + fi0) * 512;
  const float* s1 = srcA + ((size_t)mm1 * 514 + 2 + fi1) * 512;
  float4 a0 = *(const float4*)(s0 + l * 4);
  float4 a1 = *(const float4*)(s0 + 256 + l * 4);
  float4 c0 = *(const float4*)(s1 + l * 4);
  float4 c1 = *(const float4*)(s1 + 256 + l * 4);
  x0[0]=a0.x; x0[1]=a0.y; x0[2]=a0.z; x0[3]=a0.w;
  x0[4]=a1.x; x0[5]=a1.y; x0[6]=a1.z; x0[7]=a1.w;
  x1[0]=c0.x; x1[1]=c0.y; x1[2]=c0.z; x1[3]=c0.w;
  x1[4]=c1.x; x1[5]=c1.y; x1[6]=c1.z; x1[7]=c1.w;
  float s0v = 0.f, q0 = 0.f, s1v = 0.f, q1 = 0.f;
  #pragma unroll
  for (int j = 0; j < 8; ++j) {
    s0v += x0[j]; q0 += x0[j] * x0[j];
    s1v += x1[j]; q1 += x1[j] * x1[j];
  }
  #pragma unroll
  for (int o = 1; o < 64; o <<= 1) {
    s0v += __shfl_xor(s0v, o); q0 += __shfl_xor(q0, o);
    s1v += __shfl_xor(s1v, o); q1 += __shfl_xor(q1, o);
  }
  float mu0 = s0v * (1.f/512.f), mu1 = s1v * (1.f/512.f);
  float rstd0 = rsqrtf(q0 * (1.f/512.f) - mu0 * mu0 + 1e-5f);
  float rstd1 = rsqrtf(q1 * (1.f/512.f) - mu1 * mu1 + 1e-5f);
  float4 g0 = *(const float4*)(g + l * 4);
  float4 g1v = *(const float4*)(g + 256 + l * 4);
  float4 b0 = *(const float4*)(b + l * 4);
  float4 b1v = *(const float4*)(b + 256 + l * 4);
  float gv[8] = {g0.x,g0.y,g0.z,g0.w,g1v.x,g1v.y,g1v.z,g1v.w};
  float bv[8] = {b0.x,b0.y,b0.z,b0.w,b1v.x,b1v.y,b1v.z,b1v.w};
  ushort* d0 = dst + (size_t)r0 * 512;
  ushort* d1 = dst + (size_t)r1 * 512;
  ushort4v p00, p01, p10, p11;
  #pragma unroll
  for (int j = 0; j < 4; ++j) {
    p00[j] = f2bf((x0[j]-mu0)*rstd0*gv[j]+bv[j]);
    p01[j] = f2bf((x0[4+j]-mu0)*rstd0*gv[4+j]+bv[4+j]);
    p10[j] = f2bf((x1[j]-mu1)*rstd1*gv[j]+bv[j]);
    p11[j] = f2bf((x1[4+j]-mu1)*rstd1*gv[4+j]+bv[4+j]);
  }
  *(ushort4v*)(d0 + l * 4) = p00;
  *(ushort4v*)(d0 + 256 + l * 4) = p01;
  *(ushort4v*)(d1 + l * 4) = p10;
  *(ushort4v*)(d1 + 256 + l * 4) = p11;
}

// ---------------------------------------------------------------------------
// Preamble: blocks 0-639 cast 5 weights, 640-671 ln0 (video), 672+ ln1 music.
// ---------------------------------------------------------------------------
struct PreArgs {
  const float* s0; const float* s1; const float* s2; const float* s3; const float* s4;
  ushort* d0; ushort* d1; ushort* d2; ushort* d3; ushort* d4;
  const float* video; const float* music;
  const float* g1; const float* b1;
  ushort* veln; ushort* mfln;
};
__global__ __launch_bounds__(256) void preamble(PreArgs a) {
  int bb = blockIdx.x;
  if (bb < 640) {
    int t = bb * 256 + threadIdx.x;
    int which = t >> 15;
    int e = (t & 32767) * 8;
    const float* s = which == 0 ? a.s0 : which == 1 ? a.s1 : which == 2 ? a.s2 : which == 3 ? a.s3 : a.s4;
    ushort*      d = which == 0 ? a.d0 : which == 1 ? a.d1 : which == 2 ? a.d2 : which == 3 ? a.d3 : a.d4;
    float4 v0 = *(const float4*)(s + e);
    float4 v1 = *(const float4*)(s + e + 4);
    uint4 o;
    o.x = (uint)f2bf(v0.x) | ((uint)f2bf(v0.y) << 16);
    o.y = (uint)f2bf(v0.z) | ((uint)f2bf(v0.w) << 16);
    o.z = (uint)f2bf(v1.x) | ((uint)f2bf(v1.y) << 16);
    o.w = (uint)f2bf(v1.z) | ((uint)f2bf(v1.w) << 16);
    *(uint4*)(d + e) = o;
  } else if (bb < 672) {
    ln_rows0(128, bb - 640, 32, threadIdx.x, a.video, a.g1, a.b1, a.veln);
  } else {
    ln_pair1((bb - 672) * 4 + (threadIdx.x >> 6), threadIdx.x,
             a.music, a.g1, a.b1, a.mfln);
  }
}

// ---------------------------------------------------------------------------
// Fused K+V(+Q) projection (R9/R11-proven). BM=256, BN=128 per output,
// BK=64, 512 threads = 8 waves (4 row x 2 col), double-buffered 128 KB LDS.
// grid (4, 257): y<256 kv blocks; y==256 q block.
// ---------------------------------------------------------------------------
__global__ __launch_bounds__(512) void gemm_kvq(
    const ushort* __restrict__ Amf, const ushort* __restrict__ Aq,
    const ushort* __restrict__ Wk, const ushort* __restrict__ Wv,
    const ushort* __restrict__ Wq,
    const float* __restrict__ bk, const float* __restrict__ bv,
    const float* __restrict__ bq,
    ushort* __restrict__ K, ushort* __restrict__ Vt, ushort* __restrict__ Q)
{
  __shared__ __align__(16) ushort As[2][256 * 64];
  __shared__ __align__(16) ushort Bks[2][128 * 64];
  __shared__ __align__(16) ushort Bvs[2][128 * 64];
  const int tid = threadIdx.x;
  const int w = tid >> 6, l = tid & 63;
  const int lg = l >> 4, lr = l & 15;
  const int wr = w >> 1, wc = w & 1;

  const bool isq = (blockIdx.y == 256);
  const int row0 = isq ? 0 : blockIdx.y * 256;
  const int col0 = blockIdx.x * 128;
  const ushort* Ap  = isq ? Aq : Amf;
  const ushort* Wkp = isq ? Wq : Wk;

  f32x4 kacc[4][4], vacc[4][4];
  #pragma unroll
  for (int i = 0; i < 4; i++)
    #pragma unroll
    for (int j = 0; j < 4; j++) {
      f32x4 z = {0.f,0.f,0.f,0.f};
      kacc[i][j] = z; vacc[i][j] = z;
    }

  size_t asrc[4], wksrc[2]; int aldst[4], wldst[2];
  {
    int r = tid >> 3, j = tid & 7;
    int koff = (j ^ (r & 7)) * 8;
    #pragma unroll
    for (int c2 = 0; c2 < 4; ++c2) {
      asrc[c2] = (size_t)(row0 + c2 * 64 + r) * 512 + koff;
      aldst[c2] = ((c2 * 64 + w * 8) * 64);
    }
    #pragma unroll
    for (int c2 = 0; c2 < 2; ++c2) {
      wksrc[c2] = (size_t)(col0 + c2 * 64 + r) * 512 + koff;
      wldst[c2] = ((c2 * 64 + w * 8) * 64);
    }
  }

  auto stage = [&](int pb, int kk) {
    #pragma unroll
    for (int c2 = 0; c2 < 4; ++c2)
      gl2lds16(Ap + asrc[c2] + kk * 64, &As[pb][aldst[c2]]);
    #pragma unroll
    for (int c2 = 0; c2 < 2; ++c2) {
      gl2lds16(Wkp + wksrc[c2] + kk * 64, &Bks[pb][wldst[c2]]);
      gl2lds16(Wv + wksrc[c2] + kk * 64, &Bvs[pb][wldst[c2]]);
    }
  };
  auto compute = [&](int pb) {
    #pragma unroll
    for (int ks = 0; ks < 2; ++ks) {
      bf16x8 af[4], bkf[4];
      #pragma unroll
      for (int mi = 0; mi < 4; ++mi) {
        int r = wr * 64 + mi * 16 + lr;
        af[mi] = *(const bf16x8*)(&As[pb][r * 64 + ((ks * 32 + lg * 8) ^ ((r & 7) * 8))]);
      }
      #pragma unroll
      for (int ni = 0; ni < 4; ++ni) {
        int r = wc * 64 + ni * 16 + lr;
        bkf[ni] = *(const bf16x8*)(&Bks[pb][r * 64 + ((ks * 32 + lg * 8) ^ ((r & 7) * 8))]);
      }
      #pragma unroll
      for (int mi = 0; mi < 4; ++mi)
        #pragma unroll
        for (int ni = 0; ni < 4; ++ni)
          kacc[mi][ni] = __builtin_amdgcn_mfma_f32_16x16x32_bf16(af[mi], bkf[ni], kacc[mi][ni], 0, 0, 0);
      if (!isq) {
        bf16x8 bvf[4];
        #pragma unroll
        for (int ni = 0; ni < 4; ++ni) {
          int r = wc * 64 + ni * 16 + lr;
          bvf[ni] = *(const bf16x8*)(&Bvs[pb][r * 64 + ((ks * 32 + lg * 8) ^ ((r & 7) * 8))]);
        }
        #pragma unroll
        for (int mi = 0; mi < 4; ++mi)
          #pragma unroll
          for (int ni = 0; ni < 4; ++ni)
            vacc[mi][ni] = __builtin_amdgcn_mfma_f32_16x16x32_bf16(af[mi], bvf[ni], vacc[mi][ni], 0, 0, 0);
      }
    }
  };

  stage(0, 0);
  __syncthreads();
  int cur = 0;
  #pragma unroll
  for (int kk = 0; kk < 7; ++kk) {
    stage(cur ^ 1, kk + 1);
    compute(cur);
    __syncthreads();
    cur ^= 1;
  }
  compute(cur);

  #pragma unroll
  for (int ni = 0; ni < 4; ++ni) {
    int cg = col0 + wc * 64 + ni * 16 + lr;
    float bkc = isq ? bq[cg] : bk[cg];
    float bvc = isq ? 0.f : bv[cg];
    #pragma unroll
    for (int mi = 0; mi < 4; ++mi) {
      int rg0 = row0 + wr * 64 + mi * 16 + lg * 4;
      if (isq) {
        if (rg0 < 128) {
          #pragma unroll
          for (int e = 0; e < 4; ++e)
            Q[(size_t)(rg0 + e) * 512 + cg] = f2bf((kacc[mi][ni][e] + bkc) * 0.125f);
        }
      } else {
        #pragma unroll
        for (int e = 0; e < 4; ++e)
          K[(size_t)(rg0 + e) * 512 + cg] = f2bf(kacc[mi][ni][e] + bkc);
        int m = rg0 >> 9, fi = rg0 & 511;
        ushort4v pk;
        #pragma unroll
        for (int e = 0; e < 4; ++e) pk[e] = f2bf(vacc[mi][ni][e] + bvc);
        *(ushort4v*)(Vt + (size_t)(m * 512 + cg) * 512 + fi) = pk;
      }
    }
  }
}

// ---------------------------------------------------------------------------
// Fused GEMM + row-LayerNorm (R11-proven). BM=64, BN=512, BK=64, 8 waves.
// outf32=0: out = bf16 LN(A@W^T + bias)              [Wo + ln2]
// outf32=1: out = f32  LN(resid + A@W^T + bias)      [Wl + residual + ln3]
// ---------------------------------------------------------------------------
__global__ __launch_bounds__(512) void gemm_ln(
    const ushort* __restrict__ A, const ushort* __restrict__ W,
    const float* __restrict__ bias,
    const float* __restrict__ gam, const float* __restrict__ bet,
    void* __restrict__ outp, const ushort* __restrict__ resid, int outf32)
{
  __shared__ __align__(16) ushort As[2][64 * 64];
  __shared__ __align__(16) ushort Bs[2][512 * 64];
  __shared__ float red[8][64][2];
  const int tid = threadIdx.x;
  const int w = tid >> 6, l = tid & 63;
  const int lg = l >> 4, lr = l & 15;
  const int row0 = blockIdx.x * 64;

  f32x4 acc[4][4];
  #pragma unroll
  for (int i = 0; i < 4; i++)
    #pragma unroll
    for (int j = 0; j < 4; j++) { f32x4 z = {0.f,0.f,0.f,0.f}; acc[i][j] = z; }

  size_t asrc, wsrc0; int aldst;
  {
    int r = tid >> 3, j = tid & 7;
    int koff = (j ^ (r & 7)) * 8;
    asrc = (size_t)(row0 + r) * 512 + koff;
    wsrc0 = (size_t)r * 512 + koff;
    aldst = (w * 8) * 64;
  }

  auto stage = [&](int pb, int kk) {
    gl2lds16(A + asrc + kk * 64, &As[pb][aldst]);
    #pragma unroll
    for (int b = 0; b < 8; ++b)
      gl2lds16(W + wsrc0 + (size_t)b * 32768 + kk * 64,
               &Bs[pb][(b * 64 + w * 8) * 64]);
  };
  auto compute = [&](int pb) {
    #pragma unroll
    for (int ks = 0; ks < 2; ++ks) {
      bf16x8 af[4], bfr[4];
      #pragma unroll
      for (int mi = 0; mi < 4; ++mi) {
        int ra = mi * 16 + lr;
        af[mi] = *(const bf16x8*)(&As[pb][ra * 64 + ((ks * 32 + lg * 8) ^ ((ra & 7) * 8))]);
      }
      #pragma unroll
      for (int ni = 0; ni < 4; ++ni) {
        int rb = w * 64 + ni * 16 + lr;
        bfr[ni] = *(const bf16x8*)(&Bs[pb][rb * 64 + ((ks * 32 + lg * 8) ^ ((rb & 7) * 8))]);
      }
      __builtin_amdgcn_s_setprio(1);
      #pragma unroll
      for (int mi = 0; mi < 4; ++mi)
        #pragma unroll
        for (int ni = 0; ni < 4; ++ni)
          acc[mi][ni] = __builtin_amdgcn_mfma_f32_16x16x32_bf16(af[mi], bfr[ni], acc[mi][ni], 0, 0, 0);
      __builtin_amdgcn_s_setprio(0);
    }
  };

  stage(0, 0);
  __syncthreads();
  int cur = 0;
  #pragma unroll
  for (int kk = 0; kk < 7; ++kk) {
    stage(cur ^ 1, kk + 1);
    compute(cur);
    __syncthreads();
    cur ^= 1;
  }
  compute(cur);

  float bc[4], gv[4], bv2[4];
  #pragma unroll
  for (int ni = 0; ni < 4; ++ni) {
    int col = w * 64 + ni * 16 + lr;
    bc[ni] = bias[col];
    gv[ni] = gam[col];
    bv2[ni] = bet[col];
  }
  #pragma unroll
  for (int mi = 0; mi < 4; ++mi)
    #pragma unroll
    for (int e = 0; e < 4; ++e) {
      int row = row0 + mi * 16 + lg * 4 + e;
      #pragma unroll
      for (int ni = 0; ni < 4; ++ni) {
        float v = acc[mi][ni][e] + bc[ni];
        if (resid) v += bf2f(resid[(size_t)row * 512 + w * 64 + ni * 16 + lr]);
        acc[mi][ni][e] = v;
      }
    }
  #pragma unroll
  for (int mi = 0; mi < 4; ++mi)
    #pragma unroll
    for (int e = 0; e < 4; ++e) {
      float s = acc[mi][0][e] + acc[mi][1][e] + acc[mi][2][e] + acc[mi][3][e];
      float q = acc[mi][0][e]*acc[mi][0][e] + acc[mi][1][e]*acc[mi][1][e]
              + acc[mi][2][e]*acc[mi][2][e] + acc[mi][3][e]*acc[mi][3][e];
      #pragma unroll
      for (int o = 1; o < 16; o <<= 1) { s += __shfl_xor(s, o); q += __shfl_xor(q, o); }
      if (lr == 0) {
        int row = mi * 16 + lg * 4 + e;
        red[w][row][0] = s;
        red[w][row][1] = q;
      }
    }
  __syncthreads();
  #pragma unroll
  for (int mi = 0; mi < 4; ++mi)
    #pragma unroll
    for (int e = 0; e < 4; ++e) {
      int row = mi * 16 + lg * 4 + e;
      float S = 0.f, Qm = 0.f;
      #pragma unroll
      for (int w2 = 0; w2 < 8; ++w2) { S += red[w2][row][0]; Qm += red[w2][row][1]; }
      float mu = S * (1.f / 512.f);
      float var = Qm * (1.f / 512.f) - mu * mu;
      float rstd = rsqrtf(var + 1e-5f);
      int grow = row0 + row;
      if (!outf32) {
        ushort* o = (ushort*)outp;
        #pragma unroll
        for (int ni = 0; ni < 4; ++ni)
          o[(size_t)grow * 512 + w * 64 + ni * 16 + lr] =
              f2bf((acc[mi][ni][e] - mu) * rstd * gv[ni] + bv2[ni]);
      } else {
        float* o = (float*)outp;
        #pragma unroll
        for (int ni = 0; ni < 4; ++ni)
          o[(size_t)grow * 512 + w * 64 + ni * 16 + lr] =
              (acc[mi][ni][e] - mu) * rstd * gv[ni] + bv2[ni];
      }
    }
}

// ---------------------------------------------------------------------------
// Attention: one block per (m,h). 4 waves x 32 v-rows. Flash-style over f.
// K/V staging double-buffered; defer-max (T13). (R9-proven)
// ---------------------------------------------------------------------------
__global__ __launch_bounds__(256) void attn_kernel(
    const ushort* __restrict__ q, const ushort* __restrict__ k,
    const ushort* __restrict__ vt, const int* __restrict__ masks,
    ushort* __restrict__ attn)
{
  __shared__ __align__(16) ushort Qs[128 * 64];
  __shared__ __align__(16) ushort Ks[2][64 * 64];
  __shared__ __align__(16) ushort Vs[2][64 * 64];
  __shared__ __align__(16) ushort Ps[4][32 * 64];
  __shared__ float maskf[2][64];
  __shared__ float stats[4][32];

  const int tid = threadIdx.x;
  const int w = tid >> 6, l = tid & 63;
  const int lg = l >> 4, lr = l & 15;
  const int m = blockIdx.x >> 3, h = blockIdx.x & 7;

  const size_t kbase = (size_t)(m * 512) * 512 + h * 64;
  const size_t vbase = (size_t)(m * 512 + h * 64) * 512;

  auto stageKV = [&](int pb, int it) {
    const int f0 = it * 64;
    #pragma unroll
    for (int c2 = 0; c2 < 2; ++c2) {
      int c = c2 * 256 + tid;
      int r = c >> 3, j = c & 7;
      int off = (j * 8) ^ ((r & 7) * 8);
      gl2lds16(k + kbase + (size_t)(f0 + r) * 512 + off, &Ks[pb][(c2 * 256 + w * 64) * 8]);
      gl2lds16(vt + vbase + (size_t)r * 512 + f0 + off, &Vs[pb][(c2 * 256 + w * 64) * 8]);
    }
    if (tid < 64) maskf[pb][tid] = masks[m * 512 + f0 + tid] ? 0.f : -1e30f;
  };

  #pragma unroll
  for (int c2 = 0; c2 < 4; ++c2) {
    int c = c2 * 256 + tid;
    int r = c >> 3, j = c & 7;
    gl2lds16(q + (size_t)r * 512 + h * 64 + ((j * 8) ^ ((r & 7) * 8)),
             Qs + (c2 * 256 + w * 64) * 8);
  }
  stageKV(0, 0);
  __syncthreads();

  f32x4 acc[2][4];
  #pragma unroll
  for (int i = 0; i < 2; i++)
    #pragma unroll
    for (int j = 0; j < 4; j++) { f32x4 z = {0.f,0.f,0.f,0.f}; acc[i][j] = z; }
  float m_run[2] = {-INFINITY, -INFINITY};
  float l_run[2] = {0.f, 0.f};
  bf16x8 qf[2][2];
  #pragma unroll
  for (int nv = 0; nv < 2; ++nv)
    #pragma unroll
    for (int k2 = 0; k2 < 2; ++k2) {
      int v = w * 32 + nv * 16 + lr;
      qf[nv][k2] = *(const bf16x8*)(Qs + v * 64 + ((k2 * 32 + lg * 8) ^ ((v & 7) * 8)));
    }

  int cur = 0;
  for (int it = 0; it < 8; ++it) {
    if (it < 7) stageKV(cur ^ 1, it + 1);

    f32x4 s[4][2];
    #pragma unroll
    for (int mi = 0; mi < 4; mi++)
      #pragma unroll
      for (int nv = 0; nv < 2; nv++) { f32x4 z = {0.f,0.f,0.f,0.f}; s[mi][nv] = z; }
    #pragma unroll
    for (int k2 = 0; k2 < 2; ++k2) {
      bf16x8 kf[4];
      #pragma unroll
      for (int mi = 0; mi < 4; ++mi) {
        int f = mi * 16 + lr;
        kf[mi] = *(const bf16x8*)(&Ks[cur][f * 64 + ((k2 * 32 + lg * 8) ^ ((f & 7) * 8))]);
      }
      __builtin_amdgcn_s_setprio(1);
      #pragma unroll
      for (int mi = 0; mi < 4; ++mi)
        #pragma unroll
        for (int nv = 0; nv < 2; ++nv)
          s[mi][nv] = __builtin_amdgcn_mfma_f32_16x16x32_bf16(kf[mi], qf[nv][k2], s[mi][nv], 0, 0, 0);
      __builtin_amdgcn_s_setprio(0);
    }

    float mk[4][4];
    #pragma unroll
    for (int mi = 0; mi < 4; mi++)
      #pragma unroll
      for (int e = 0; e < 4; e++) mk[mi][e] = maskf[cur][mi * 16 + lg * 4 + e];

    #pragma unroll
    for (int nv = 0; nv < 2; ++nv) {
      float pmax = -INFINITY;
      #pragma unroll
      for (int mi = 0; mi < 4; mi++)
        #pragma unroll
        for (int e = 0; e < 4; e++) {
          s[mi][nv][e] += mk[mi][e];
          pmax = fmaxf(pmax, s[mi][nv][e]);
        }
      pmax = fmaxf(pmax, __shfl_xor(pmax, 16));
      pmax = fmaxf(pmax, __shfl_xor(pmax, 32));
      bool skip = __all(pmax - m_run[nv] <= 8.f);
      float mnew = skip ? m_run[nv] : fmaxf(m_run[nv], pmax);
      float sc = skip ? 1.f : __expf(m_run[nv] - mnew);
      float csum = 0.f;
      int vloc = nv * 16 + lr;
      #pragma unroll
      for (int mi = 0; mi < 4; mi++) {
        ushort4v pk;
        #pragma unroll
        for (int e = 0; e < 4; e++) {
          float p = __expf(s[mi][nv][e] - mnew);
          csum += p;
          pk[e] = f2bf(p);
        }
        int f = mi * 16 + lg * 4;
        *(ushort4v*)(&Ps[w][vloc * 64 + (f ^ ((vloc & 7) * 8))]) = pk;
      }
      csum += __shfl_xor(csum, 16);
      csum += __shfl_xor(csum, 32);
      l_run[nv] = l_run[nv] * sc + csum;
      m_run[nv] = mnew;
      if (lg == 0) stats[w][vloc] = sc;
      if (!skip) {
        int mi2 = nv;
        #pragma unroll
        for (int e = 0; e < 4; ++e) {
          float scv = stats[w][mi2 * 16 + lg * 4 + e];
          #pragma unroll
          for (int nd = 0; nd < 4; ++nd) acc[mi2][nd][e] *= scv;
        }
      }
    }

    #pragma unroll
    for (int k2 = 0; k2 < 2; ++k2) {
      bf16x8 pf[2], vf[4];
      #pragma unroll
      for (int mi2 = 0; mi2 < 2; ++mi2) {
        int vloc = mi2 * 16 + lr;
        pf[mi2] = *(const bf16x8*)(&Ps[w][vloc * 64 + ((k2 * 32 + lg * 8) ^ ((vloc & 7) * 8))]);
      }
      #pragma unroll
      for (int nd = 0; nd < 4; ++nd) {
        int d = nd * 16 + lr;
        vf[nd] = *(const bf16x8*)(&Vs[cur][d * 64 + ((k2 * 32 + lg * 8) ^ ((d & 7) * 8))]);
      }
      __builtin_amdgcn_s_setprio(1);
      #pragma unroll
      for (int mi2 = 0; mi2 < 2; ++mi2)
        #pragma unroll
        for (int nd = 0; nd < 4; ++nd)
          acc[mi2][nd] = __builtin_amdgcn_mfma_f32_16x16x32_bf16(pf[mi2], vf[nd], acc[mi2][nd], 0, 0, 0);
      __builtin_amdgcn_s_setprio(0);
    }
    __syncthreads();
    cur ^= 1;
  }

  #pragma unroll
  for (int nv = 0; nv < 2; ++nv)
    if (lg == 0) stats[w][nv * 16 + lr] = 1.f / l_run[nv];
  #pragma unroll
  for (int mi2 = 0; mi2 < 2; ++mi2)
    #pragma unroll
    for (int e = 0; e < 4; ++e) {
      float invl = stats[w][mi2 * 16 + lg * 4 + e];
      int vg = w * 32 + mi2 * 16 + lg * 4 + e;
      #pragma unroll
      for (int nd = 0; nd < 4; ++nd) {
        int d = nd * 16 + lr;
        attn[(size_t)(vg * 128 + m) * 512 + h * 64 + d] = f2bf(acc[mi2][nd][e] * invl);
      }
    }
}

// ---------------------------------------------------------------------------
extern "C" void kernel_launch(void* const* d_in, const int* in_sizes, int n_in,
                              void* d_out, int out_size, void* d_ws, size_t ws_size,
                              hipStream_t stream) {
  const float* video = (const float*)d_in[0];
  const float* music = (const float*)d_in[1];
  const int*   masks = (const int*)d_in[2];
  const float* Wq = (const float*)d_in[3];
  const float* Wk = (const float*)d_in[4];
  const float* Wv = (const float*)d_in[5];
  const float* Wo = (const float*)d_in[6];
  const float* Wl = (const float*)d_in[7];
  const float* bq = (const float*)d_in[8];
  const float* bk = (const float*)d_in[9];
  const float* bv = (const float*)d_in[10];
  const float* bo = (const float*)d_in[11];
  const float* bl = (const float*)d_in[12];
  const float* g1 = (const float*)d_in[13];
  const float* g2 = (const float*)d_in[14];
  const float* g3 = (const float*)d_in[15];
  const float* b1 = (const float*)d_in[16];
  const float* b2 = (const float*)d_in[17];
  const float* b3 = (const float*)d_in[18];

  char* ws = (char*)d_ws;
  ushort* mfln = (ushort*)(ws);                    // 65536x512 bf16
  ushort* kbuf = (ushort*)(ws + 67108864);         // 65536x512 bf16
  ushort* vtb  = (ushort*)(ws + 134217728);        // 65536x512 bf16 (transposed per m)
  ushort* attn = (ushort*)(ws + 201326592);        // 16384x512 bf16
  ushort* xbuf = (ushort*)(ws + 234881024);        // 16384x512 bf16
  ushort* veln = (ushort*)(ws + 251658240);        // 128x512 bf16
  ushort* qbuf = (ushort*)(ws + 251789312);        // 128x512 bf16
  ushort* wqb  = (ushort*)(ws + 251920384);
  ushort* wkb  = wqb + 262144;
  ushort* wvb  = wkb + 262144;
  ushort* wob  = wvb + 262144;
  ushort* wlb  = wob + 262144;

  PreArgs pa = {Wq, Wk, Wv, Wo, Wl, wqb, wkb, wvb, wob, wlb,
                video, music, g1, b1, veln, mfln};
  preamble<<<8864, 256, 0, stream>>>(pa);

  gemm_kvq<<<dim3(4, 257), 512, 0, stream>>>(
      mfln, veln, wkb, wvb, wqb, bk, bv, bq, kbuf, vtb, qbuf);

  attn_kernel<<<1024, 256, 0, stream>>>(qbuf, kbuf, vtb, masks, attn);

  gemm_ln<<<256, 512, 0, stream>>>(attn, wob, bo, g2, b2, xbuf, nullptr, 0);
  gemm_ln<<<256, 512, 0, stream>>>(xbuf, wlb, bl, g3, b3, d_out, xbuf, 1);
}